// Round 7
// baseline (295.501 us; speedup 1.0000x reference)
//
#include <hip/hip_runtime.h>
#include <math.h>

// Problem constants (match reference)
#define BB   16
#define NN_  256
#define NSH  16

// Native clang vector type: __builtin_nontemporal_store requires it
// (HIP's float4 is a class and is rejected).
typedef float f4 __attribute__((ext_vector_type(4)));

// Thread mapping: 4 threads per (b,i,j) pair; thread q of a pair owns
// shifts [4q, 4q+4). All global stores are lane-contiguous full 64B sectors.
// Fast-math intrinsics: tolerance is 0.03125 absmax; __expf/v_rcp add <=1e-4.
__global__ __launch_bounds__(256) void aev_sv_kernel(
    const float* __restrict__ coord,   // [B, N, 3]
    const float* __restrict__ shifts,  // [16]
    const float* __restrict__ eta_p,   // [1]
    const float* __restrict__ rc_p,    // [1]
    float* __restrict__ out)           // d_ij | gs | gv concatenated
{
    const int tid = blockIdx.x * blockDim.x + threadIdx.x;  // [0, 4*B*N*N)
    const int p = tid >> 2;            // pair index [0, B*N*N)
    const int q = tid & 3;             // quad of shifts
    const int b  = p >> 16;
    const int ij = p & 65535;
    const int i  = ij >> 8;
    const int j  = ij & 255;

    const float rc  = rc_p[0];
    const float eta = eta_p[0];

    const float* ci = coord + (b * NN_ + i) * 3;
    const float* cj = coord + (b * NN_ + j) * 3;
    // r_ij = coord[b,j] - coord[b,i]
    const float dx = cj[0] - ci[0];
    const float dy = cj[1] - ci[1];
    const float dz = cj[2] - ci[2];
    const float sq = dx * dx + dy * dy + dz * dz;

    const float inv_rc = __builtin_amdgcn_rcpf(rc);   // v_rcp_f32, ~1 ulp

    float d, fc;
    if (i == j) {
        d  = rc;      // dmat_fill
        fc = 0.0f;    // masked on diagonal
    } else {
        d  = sqrtf(sq);
        // fc = 0.5*cos(pi*d/rc)+0.5 for d<rc else 0; cospif = cos(pi*x)
        fc = (d < rc) ? (0.5f * cospif(d * inv_rc) + 0.5f) : 0.0f;
    }

    const float inv_d = __builtin_amdgcn_rcpf(d);  // diagonal: dx=dy=dz=0 -> u=0
    const float ux = dx * inv_d;
    const float uy = dy * inv_d;
    const float uz = dz * inv_d;

    // 4 Gaussians for this thread's quad of shifts (fast exp: v_exp_f32 path)
    const float4 sh = ((const float4*)shifts)[q];
    const float neta = -eta;
    const float t0 = d - sh.x, t1 = d - sh.y, t2 = d - sh.z, t3 = d - sh.w;
    const float g0 = __expf(neta * t0 * t0) * fc;
    const float g1 = __expf(neta * t1 * t1) * fc;
    const float g2 = __expf(neta * t2 * t2) * fc;
    const float g3 = __expf(neta * t3 * t3) * fc;

    // ---- stores (all lane-contiguous; nontemporal: streaming, never re-read) ----
    constexpr int BNN = BB * NN_ * NN_;               // 1,048,576 (d_ij elems)
    constexpr size_t GS_OFF = (size_t)BNN;            // float offset of gs
    constexpr size_t GV_OFF = GS_OFF + (size_t)BNN * NSH;  // float offset of gv

    // d_ij: one lane per pair (q==0); active lanes write contiguous floats
    if (q == 0) __builtin_nontemporal_store(d, out + p);

    // gs: [B,N,N,16] -> f4 index p*4 + q == tid (consecutive lanes contiguous)
    f4* gs_out = (f4*)(out + GS_OFF);
    f4 gsv; gsv.x = g0; gsv.y = g1; gsv.z = g2; gsv.w = g3;
    __builtin_nontemporal_store(gsv, gs_out + tid);

    // gv: [B,N,N,3,16] -> f4 index p*12 + c*4 + q
    f4* gv_out = (f4*)(out + GV_OFF);
    f4 vx; vx.x = g0 * ux; vx.y = g1 * ux; vx.z = g2 * ux; vx.w = g3 * ux;
    f4 vy; vy.x = g0 * uy; vy.y = g1 * uy; vy.z = g2 * uy; vy.w = g3 * uy;
    f4 vz; vz.x = g0 * uz; vz.y = g1 * uz; vz.z = g2 * uz; vz.w = g3 * uz;
    __builtin_nontemporal_store(vx, gv_out + (p * 12 + 0 * 4 + q));
    __builtin_nontemporal_store(vy, gv_out + (p * 12 + 1 * 4 + q));
    __builtin_nontemporal_store(vz, gv_out + (p * 12 + 2 * 4 + q));
}

extern "C" void kernel_launch(void* const* d_in, const int* in_sizes, int n_in,
                              void* d_out, int out_size, void* d_ws, size_t ws_size,
                              hipStream_t stream) {
    const float* coord  = (const float*)d_in[0];
    const float* shifts = (const float*)d_in[1];
    const float* eta    = (const float*)d_in[2];
    const float* rc     = (const float*)d_in[3];
    float* out = (float*)d_out;

    const int total = BB * NN_ * NN_ * 4;       // 4,194,304 threads
    const int block = 256;
    const int grid  = total / block;            // 16384
    aev_sv_kernel<<<grid, block, 0, stream>>>(coord, shifts, eta, rc, out);
}

// Round 8
// 263.892 us; speedup vs baseline: 1.1198x; 1.1198x over previous
//
#include <hip/hip_runtime.h>
#include <math.h>

// Problem constants (match reference)
#define BB   16
#define NN_  256
#define NSH  16

// Thread mapping: 4 threads per (b,i,j) pair; thread q of a pair owns
// shifts [4q, 4q+4). All global stores are lane-contiguous full 64B sectors.
// NOTE: nontemporal stores were tried (round 7) and REGRESSED +25% — nt
// bypasses L2 write-combining on gfx950; keep normal cached stores.
__global__ __launch_bounds__(256) void aev_sv_kernel(
    const float* __restrict__ coord,   // [B, N, 3]
    const float* __restrict__ shifts,  // [16]
    const float* __restrict__ eta_p,   // [1]
    const float* __restrict__ rc_p,    // [1]
    float* __restrict__ out)           // d_ij | gs | gv concatenated
{
    const int tid = blockIdx.x * blockDim.x + threadIdx.x;  // [0, 4*B*N*N)
    const int p = tid >> 2;            // pair index [0, B*N*N)
    const int q = tid & 3;             // quad of shifts
    const int b  = p >> 16;
    const int ij = p & 65535;
    const int i  = ij >> 8;
    const int j  = ij & 255;

    const float rc  = rc_p[0];
    const float eta = eta_p[0];

    const float* ci = coord + (b * NN_ + i) * 3;
    const float* cj = coord + (b * NN_ + j) * 3;
    // r_ij = coord[b,j] - coord[b,i]
    const float dx = cj[0] - ci[0];
    const float dy = cj[1] - ci[1];
    const float dz = cj[2] - ci[2];
    const float sq = dx * dx + dy * dy + dz * dz;

    const float inv_rc = __builtin_amdgcn_rcpf(rc);   // v_rcp_f32, ~1 ulp

    float d, fc;
    if (i == j) {
        d  = rc;      // dmat_fill
        fc = 0.0f;    // masked on diagonal
    } else {
        d  = sqrtf(sq);
        // fc = 0.5*cos(pi*d/rc)+0.5 for d<rc else 0; cospif = cos(pi*x)
        fc = (d < rc) ? (0.5f * cospif(d * inv_rc) + 0.5f) : 0.0f;
    }

    const float inv_d = __builtin_amdgcn_rcpf(d);  // diagonal: dx=dy=dz=0 -> u=0
    const float ux = dx * inv_d;
    const float uy = dy * inv_d;
    const float uz = dz * inv_d;

    // 4 Gaussians for this thread's quad of shifts (fast exp: v_exp_f32 path)
    const float4 sh = ((const float4*)shifts)[q];
    const float neta = -eta;
    const float t0 = d - sh.x, t1 = d - sh.y, t2 = d - sh.z, t3 = d - sh.w;
    const float g0 = __expf(neta * t0 * t0) * fc;
    const float g1 = __expf(neta * t1 * t1) * fc;
    const float g2 = __expf(neta * t2 * t2) * fc;
    const float g3 = __expf(neta * t3 * t3) * fc;

    // ---- stores (all lane-contiguous, normal cached) ----
    constexpr int BNN = BB * NN_ * NN_;               // 1,048,576 (d_ij elems)
    constexpr size_t GS_OFF = (size_t)BNN;            // float offset of gs
    constexpr size_t GV_OFF = GS_OFF + (size_t)BNN * NSH;  // float offset of gv

    // d_ij: one lane per pair (q==0); active lanes write contiguous floats
    if (q == 0) out[p] = d;

    // gs: [B,N,N,16] -> float4 index p*4 + q == tid (consecutive lanes contiguous)
    float4* gs_out = (float4*)(out + GS_OFF);
    gs_out[tid] = make_float4(g0, g1, g2, g3);

    // gv: [B,N,N,3,16] -> float4 index p*12 + c*4 + q
    float4* gv_out = (float4*)(out + GV_OFF);
    gv_out[p * 12 + 0 * 4 + q] = make_float4(g0 * ux, g1 * ux, g2 * ux, g3 * ux);
    gv_out[p * 12 + 1 * 4 + q] = make_float4(g0 * uy, g1 * uy, g2 * uy, g3 * uy);
    gv_out[p * 12 + 2 * 4 + q] = make_float4(g0 * uz, g1 * uz, g2 * uz, g3 * uz);
}

extern "C" void kernel_launch(void* const* d_in, const int* in_sizes, int n_in,
                              void* d_out, int out_size, void* d_ws, size_t ws_size,
                              hipStream_t stream) {
    const float* coord  = (const float*)d_in[0];
    const float* shifts = (const float*)d_in[1];
    const float* eta    = (const float*)d_in[2];
    const float* rc     = (const float*)d_in[3];
    float* out = (float*)d_out;

    const int total = BB * NN_ * NN_ * 4;       // 4,194,304 threads
    const int block = 256;
    const int grid  = total / block;            // 16384
    aev_sv_kernel<<<grid, block, 0, stream>>>(coord, shifts, eta, rc, out);
}